// Round 2
// baseline (2200.694 us; speedup 1.0000x reference)
//
#include <hip/hip_runtime.h>
#include <cstddef>

#define N_NODES 100000
#define N_EDGES 500000
#define D 128  // D_IN = D_HID = D_OUT

// ---------------------------------------------------------------------------
// Scatter: for each edge e, agg[dst[e]][:] += x[src[e]][:]  (fp32 atomics)
// One thread per (edge, 4 feats): 16M threads, 4 atomicAdds each.
// add_cnt: also count in-degree (layer 1 only; graph identical both layers).
// ---------------------------------------------------------------------------
__global__ __launch_bounds__(256)
void scatter_kernel(const float* __restrict__ x,
                    const int* __restrict__ src,
                    const int* __restrict__ dst,
                    float* __restrict__ agg,
                    float* __restrict__ cnt,
                    int add_cnt)
{
    unsigned gid = blockIdx.x * blockDim.x + threadIdx.x;   // < N_EDGES*32
    unsigned e = gid >> 5;          // edge id (32 threads/edge)
    unsigned k = (gid & 31) << 2;   // feature offset 0,4,...,124
    if (e >= N_EDGES) return;
    int s = src[e];
    int d = dst[e];
    const float4 v = *reinterpret_cast<const float4*>(x + (size_t)s * D + k);
    float* a = agg + (size_t)d * D + k;
    atomicAdd(a + 0, v.x);
    atomicAdd(a + 1, v.y);
    atomicAdd(a + 2, v.z);
    atomicAdd(a + 3, v.w);
    if (add_cnt && (gid & 31u) == 0u)
        atomicAdd(cnt + d, 1.0f);
}

// ---------------------------------------------------------------------------
// Fused SAGE linear: out[i][:] = act( (agg[i]/max(cnt[i],1)) @ Wl + b
//                                      + xin[i] @ Wr )
// Treated as [aggn | xin] (Nx256) @ [Wl; Wr] (256x128).
// Tile: 32 rows x 128 cols per block, 256 threads, 4x4 register blocking.
// LDS: Ws 64x128 (32KB) + As 32x64 (8KB) per k-tile; 4 k-tiles of 64.
// In-place safe when out == xin (block reads only its own rows; writes
// happen only in the epilogue after all k-tiles are consumed).
// ---------------------------------------------------------------------------
__global__ __launch_bounds__(256)
void sage_gemm_kernel(const float* __restrict__ xin,
                      const float* __restrict__ agg,
                      const float* __restrict__ cnt,
                      const float* __restrict__ Wl,
                      const float* __restrict__ bl,
                      const float* __restrict__ Wr,
                      float* __restrict__ out,
                      int relu)
{
    __shared__ float As[32][64];    // 8 KB
    __shared__ float Ws[64][128];   // 32 KB

    const int tid = threadIdx.x;
    const int tx = tid & 31;        // col group: cols 4*tx .. 4*tx+3
    const int ty = tid >> 5;        // 0..7 ; rows ty + 8*rr
    const int row0 = blockIdx.x * 32;

    float acc[4][4] = {};

    for (int kt = 0; kt < 4; ++kt) {
        const bool is_l = (kt < 2);
        const int kbase = (kt & 1) * 64;
        const float* Wsrc = (is_l ? Wl : Wr) + (size_t)kbase * D;
        const float* Asrc = (is_l ? agg : xin) + kbase;

        __syncthreads();   // previous tile's LDS reads complete

        // stage W tile: 64x128 floats, 8 float4 per thread
        #pragma unroll
        for (int i = 0; i < 8; ++i) {
            int idx4 = i * 256 + tid;            // 0..2047
            int kk = idx4 >> 5;                  // 0..63
            int cc = (idx4 & 31) << 2;           // 0..124
            float4 w = *reinterpret_cast<const float4*>(Wsrc + (size_t)kk * D + cc);
            *reinterpret_cast<float4*>(&Ws[kk][cc]) = w;
        }
        // stage A tile: 32 rows x 64 k, 2 float4 per thread
        #pragma unroll
        for (int i = 0; i < 2; ++i) {
            int idx4 = i * 256 + tid;            // 0..511
            int r = idx4 >> 4;                   // 0..31
            int kk = (idx4 & 15) << 2;           // 0..60
            float4 a = *reinterpret_cast<const float4*>(Asrc + (size_t)(row0 + r) * D + kk);
            if (is_l) {
                float inv = 1.0f / fmaxf(cnt[row0 + r], 1.0f);
                a.x *= inv; a.y *= inv; a.z *= inv; a.w *= inv;
            }
            *reinterpret_cast<float4*>(&As[r][kk]) = a;
        }
        __syncthreads();

        // compute: per 4 k-steps: 4 w-float4 + 4 a-float4 reads, 64 FMA
        #pragma unroll
        for (int kk = 0; kk < 64; kk += 4) {
            float4 w0 = *reinterpret_cast<const float4*>(&Ws[kk + 0][tx * 4]);
            float4 w1 = *reinterpret_cast<const float4*>(&Ws[kk + 1][tx * 4]);
            float4 w2 = *reinterpret_cast<const float4*>(&Ws[kk + 2][tx * 4]);
            float4 w3 = *reinterpret_cast<const float4*>(&Ws[kk + 3][tx * 4]);
            #pragma unroll
            for (int rr = 0; rr < 4; ++rr) {
                float4 a = *reinterpret_cast<const float4*>(&As[ty + 8 * rr][kk]);
                acc[rr][0] += a.x * w0.x + a.y * w1.x + a.z * w2.x + a.w * w3.x;
                acc[rr][1] += a.x * w0.y + a.y * w1.y + a.z * w2.y + a.w * w3.y;
                acc[rr][2] += a.x * w0.z + a.y * w1.z + a.z * w2.z + a.w * w3.z;
                acc[rr][3] += a.x * w0.w + a.y * w1.w + a.z * w2.w + a.w * w3.w;
            }
        }
    }

    // epilogue: +bias, optional relu, float4 store
    float4 bias = *reinterpret_cast<const float4*>(bl + tx * 4);
    #pragma unroll
    for (int rr = 0; rr < 4; ++rr) {
        int r = row0 + ty + 8 * rr;
        float4 o;
        o.x = acc[rr][0] + bias.x;
        o.y = acc[rr][1] + bias.y;
        o.z = acc[rr][2] + bias.z;
        o.w = acc[rr][3] + bias.w;
        if (relu) {
            o.x = fmaxf(o.x, 0.0f); o.y = fmaxf(o.y, 0.0f);
            o.z = fmaxf(o.z, 0.0f); o.w = fmaxf(o.w, 0.0f);
        }
        *reinterpret_cast<float4*>(out + (size_t)r * D + tx * 4) = o;
    }
}

// ---------------------------------------------------------------------------
extern "C" void kernel_launch(void* const* d_in, const int* in_sizes, int n_in,
                              void* d_out, int out_size, void* d_ws, size_t ws_size,
                              hipStream_t stream)
{
    const float* x   = (const float*)d_in[0];
    const int*   ei  = (const int*)d_in[1];
    const int*   src = ei;              // edge_index[0]
    const int*   dst = ei + N_EDGES;    // edge_index[1]
    const float* Wl1 = (const float*)d_in[2];
    const float* bl1 = (const float*)d_in[3];
    const float* Wr1 = (const float*)d_in[4];
    const float* Wl2 = (const float*)d_in[5];
    const float* bl2 = (const float*)d_in[6];
    const float* Wr2 = (const float*)d_in[7];
    float* out = (float*)d_out;

    // workspace layout: agg (N*D f32) | cnt (N f32)   -> 51.6 MB
    float* agg = (float*)d_ws;
    float* cnt = agg + (size_t)N_NODES * D;
    const size_t agg_bytes = (size_t)N_NODES * D * sizeof(float);
    const size_t cnt_bytes = (size_t)N_NODES * sizeof(float);

    const int scat_blocks = (N_EDGES * 32) / 256;   // 62500
    const int gemm_blocks = (N_NODES + 31) / 32;    // 3125

    // ---- layer 1 ----
    hipMemsetAsync(d_ws, 0, agg_bytes + cnt_bytes, stream);
    scatter_kernel<<<scat_blocks, 256, 0, stream>>>(x, src, dst, agg, cnt, 1);
    sage_gemm_kernel<<<gemm_blocks, 256, 0, stream>>>(x, agg, cnt, Wl1, bl1, Wr1,
                                                      out, /*relu=*/1);
    // ---- layer 2 (h lives in d_out; gemm is in-place safe) ----
    hipMemsetAsync(agg, 0, agg_bytes, stream);
    scatter_kernel<<<scat_blocks, 256, 0, stream>>>(out, src, dst, agg, cnt, 0);
    sage_gemm_kernel<<<gemm_blocks, 256, 0, stream>>>(out, agg, cnt, Wl2, bl2, Wr2,
                                                      out, /*relu=*/0);
}

// Round 4
// 709.733 us; speedup vs baseline: 3.1007x; 3.1007x over previous
//
#include <hip/hip_runtime.h>
#include <cstddef>

#define N_NODES 100000
#define N_EDGES 500000
#define D 128  // D_IN = D_HID = D_OUT

// ---------------------------------------------------------------------------
// CSR build (per call, graph-capture-safe): counting sort of edges by dst.
//   deg[n]     : in-degree histogram (int)
//   row_ptr[n] : exclusive prefix sum of deg  (N+1 entries)
//   perm[p]    : src node of each edge, grouped by dst
// ---------------------------------------------------------------------------

__global__ __launch_bounds__(256)
void hist_kernel(const int* __restrict__ dst, int* __restrict__ deg)
{
    int e = blockIdx.x * 256 + threadIdx.x;
    if (e < N_EDGES) atomicAdd(&deg[dst[e]], 1);
}

// pass A: per-block (512-wide) sums of deg
__global__ __launch_bounds__(512)
void scanA_kernel(const int* __restrict__ deg, int* __restrict__ bsum)
{
    __shared__ int s[512];
    int t = threadIdx.x;
    int idx = blockIdx.x * 512 + t;
    s[t] = (idx < N_NODES) ? deg[idx] : 0;
    __syncthreads();
    for (int off = 256; off > 0; off >>= 1) {
        if (t < off) s[t] += s[t + off];
        __syncthreads();
    }
    if (t == 0) bsum[blockIdx.x] = s[0];
}

// pass B: exclusive scan of the 196 block sums (single block)
__global__ __launch_bounds__(256)
void scanB_kernel(const int* __restrict__ bsum, int* __restrict__ boff)
{
    __shared__ int s[256];
    int t = threadIdx.x;
    int v = (t < 196) ? bsum[t] : 0;
    s[t] = v;
    __syncthreads();
    for (int off = 1; off < 256; off <<= 1) {
        int a = s[t];
        if (t >= off) a += s[t - off];
        __syncthreads();
        s[t] = a;
        __syncthreads();
    }
    if (t < 196) boff[t] = s[t] - v;   // exclusive
}

// pass C: per-block inclusive scan + block offset -> row_ptr (and cursor copy)
__global__ __launch_bounds__(512)
void scanC_kernel(const int* __restrict__ deg, const int* __restrict__ boff,
                  int* __restrict__ row_ptr, int* __restrict__ cursor)
{
    __shared__ int s[512];
    int t = threadIdx.x;
    int idx = blockIdx.x * 512 + t;
    int v = (idx < N_NODES) ? deg[idx] : 0;
    s[t] = v;
    __syncthreads();
    for (int off = 1; off < 512; off <<= 1) {
        int a = s[t];
        if (t >= off) a += s[t - off];
        __syncthreads();
        s[t] = a;
        __syncthreads();
    }
    int excl = boff[blockIdx.x] + s[t] - v;
    if (idx < N_NODES) { row_ptr[idx] = excl; cursor[idx] = excl; }
    else if (idx == N_NODES) { row_ptr[idx] = excl; }
}

__global__ __launch_bounds__(256)
void permute_kernel(const int* __restrict__ src, const int* __restrict__ dst,
                    int* __restrict__ cursor, int* __restrict__ perm)
{
    int e = blockIdx.x * 256 + threadIdx.x;
    if (e < N_EDGES) {
        int pos = atomicAdd(&cursor[dst[e]], 1);
        perm[pos] = src[e];
    }
}

// ---------------------------------------------------------------------------
// Gather: agg[n][:] = (1/max(deg,1)) * sum_{e in CSR row n} x[perm[e]][:]
// 32 threads per node, one float4 per thread; each agg row written exactly
// once (no atomics, no zero-init). Unroll-4 over edges for load ILP.
// ---------------------------------------------------------------------------
__global__ __launch_bounds__(256)
void gather_kernel(const float* __restrict__ x,
                   const int* __restrict__ row_ptr,
                   const int* __restrict__ perm,
                   float* __restrict__ agg)
{
    unsigned gid = blockIdx.x * 256 + threadIdx.x;
    unsigned node = gid >> 5;           // 12500 blocks * 8 nodes = 100000 exact
    unsigned c4 = (gid & 31) << 2;      // col offset 0..124
    if (node >= N_NODES) return;
    int beg = row_ptr[node];
    int end = row_ptr[node + 1];
    float4 acc = make_float4(0.f, 0.f, 0.f, 0.f);
    int e = beg;
    for (; e + 4 <= end; e += 4) {
        int s0 = perm[e + 0], s1 = perm[e + 1], s2 = perm[e + 2], s3 = perm[e + 3];
        float4 v0 = *reinterpret_cast<const float4*>(x + (size_t)s0 * D + c4);
        float4 v1 = *reinterpret_cast<const float4*>(x + (size_t)s1 * D + c4);
        float4 v2 = *reinterpret_cast<const float4*>(x + (size_t)s2 * D + c4);
        float4 v3 = *reinterpret_cast<const float4*>(x + (size_t)s3 * D + c4);
        acc.x += (v0.x + v1.x) + (v2.x + v3.x);
        acc.y += (v0.y + v1.y) + (v2.y + v3.y);
        acc.z += (v0.z + v1.z) + (v2.z + v3.z);
        acc.w += (v0.w + v1.w) + (v2.w + v3.w);
    }
    for (; e < end; ++e) {
        int s0 = perm[e];
        float4 v0 = *reinterpret_cast<const float4*>(x + (size_t)s0 * D + c4);
        acc.x += v0.x; acc.y += v0.y; acc.z += v0.z; acc.w += v0.w;
    }
    float inv = 1.0f / fmaxf((float)(end - beg), 1.0f);
    acc.x *= inv; acc.y *= inv; acc.z *= inv; acc.w *= inv;
    *reinterpret_cast<float4*>(agg + (size_t)node * D + c4) = acc;
}

// ---------------------------------------------------------------------------
// Fused SAGE linear: out[i][:] = act( agg[i] @ Wl + b + xin[i] @ Wr )
// (agg arrives pre-normalized from gather.)
// Tile: 32 rows x 128 cols per block, 256 threads, 4x4 register blocking.
// In-place safe when out == xin (block reads only its own rows; writes
// happen only in the epilogue after all k-tiles are consumed).
// ---------------------------------------------------------------------------
__global__ __launch_bounds__(256)
void sage_gemm_kernel(const float* __restrict__ xin,
                      const float* __restrict__ agg,
                      const float* __restrict__ Wl,
                      const float* __restrict__ bl,
                      const float* __restrict__ Wr,
                      float* __restrict__ out,
                      int relu)
{
    __shared__ float As[32][64];    // 8 KB
    __shared__ float Ws[64][128];   // 32 KB

    const int tid = threadIdx.x;
    const int tx = tid & 31;        // col group: cols 4*tx .. 4*tx+3
    const int ty = tid >> 5;        // 0..7 ; rows ty + 8*rr
    const int row0 = blockIdx.x * 32;

    float acc[4][4] = {};

    for (int kt = 0; kt < 4; ++kt) {
        const bool is_l = (kt < 2);
        const int kbase = (kt & 1) * 64;
        const float* Wsrc = (is_l ? Wl : Wr) + (size_t)kbase * D;
        const float* Asrc = (is_l ? agg : xin) + kbase;

        __syncthreads();   // previous tile's LDS reads complete

        // stage W tile: 64x128 floats, 8 float4 per thread
        #pragma unroll
        for (int i = 0; i < 8; ++i) {
            int idx4 = i * 256 + tid;            // 0..2047
            int kk = idx4 >> 5;                  // 0..63
            int cc = (idx4 & 31) << 2;           // 0..124
            float4 w = *reinterpret_cast<const float4*>(Wsrc + (size_t)kk * D + cc);
            *reinterpret_cast<float4*>(&Ws[kk][cc]) = w;
        }
        // stage A tile: 32 rows x 64 k, 2 float4 per thread
        #pragma unroll
        for (int i = 0; i < 2; ++i) {
            int idx4 = i * 256 + tid;            // 0..511
            int r = idx4 >> 4;                   // 0..31
            int kk = (idx4 & 15) << 2;           // 0..60
            float4 a = *reinterpret_cast<const float4*>(Asrc + (size_t)(row0 + r) * D + kk);
            *reinterpret_cast<float4*>(&As[r][kk]) = a;
        }
        __syncthreads();

        // compute: per 4 k-steps: 4 w-float4 + 4 a-float4 reads, 64 FMA
        #pragma unroll
        for (int kk = 0; kk < 64; kk += 4) {
            float4 w0 = *reinterpret_cast<const float4*>(&Ws[kk + 0][tx * 4]);
            float4 w1 = *reinterpret_cast<const float4*>(&Ws[kk + 1][tx * 4]);
            float4 w2 = *reinterpret_cast<const float4*>(&Ws[kk + 2][tx * 4]);
            float4 w3 = *reinterpret_cast<const float4*>(&Ws[kk + 3][tx * 4]);
            #pragma unroll
            for (int rr = 0; rr < 4; ++rr) {
                float4 a = *reinterpret_cast<const float4*>(&As[ty + 8 * rr][kk]);
                acc[rr][0] += a.x * w0.x + a.y * w1.x + a.z * w2.x + a.w * w3.x;
                acc[rr][1] += a.x * w0.y + a.y * w1.y + a.z * w2.y + a.w * w3.y;
                acc[rr][2] += a.x * w0.z + a.y * w1.z + a.z * w2.z + a.w * w3.z;
                acc[rr][3] += a.x * w0.w + a.y * w1.w + a.z * w2.w + a.w * w3.w;
            }
        }
    }

    // epilogue: +bias, optional relu, float4 store
    float4 bias = *reinterpret_cast<const float4*>(bl + tx * 4);
    #pragma unroll
    for (int rr = 0; rr < 4; ++rr) {
        int r = row0 + ty + 8 * rr;
        float4 o;
        o.x = acc[rr][0] + bias.x;
        o.y = acc[rr][1] + bias.y;
        o.z = acc[rr][2] + bias.z;
        o.w = acc[rr][3] + bias.w;
        if (relu) {
            o.x = fmaxf(o.x, 0.0f); o.y = fmaxf(o.y, 0.0f);
            o.z = fmaxf(o.z, 0.0f); o.w = fmaxf(o.w, 0.0f);
        }
        *reinterpret_cast<float4*>(out + (size_t)r * D + tx * 4) = o;
    }
}

// ---------------------------------------------------------------------------
extern "C" void kernel_launch(void* const* d_in, const int* in_sizes, int n_in,
                              void* d_out, int out_size, void* d_ws, size_t ws_size,
                              hipStream_t stream)
{
    const float* x   = (const float*)d_in[0];
    const int*   ei  = (const int*)d_in[1];
    const int*   src = ei;              // edge_index[0]
    const int*   dst = ei + N_EDGES;    // edge_index[1]
    const float* Wl1 = (const float*)d_in[2];
    const float* bl1 = (const float*)d_in[3];
    const float* Wr1 = (const float*)d_in[4];
    const float* Wl2 = (const float*)d_in[5];
    const float* bl2 = (const float*)d_in[6];
    const float* Wr2 = (const float*)d_in[7];
    float* out = (float*)d_out;

    // workspace layout (ints, then aligned float agg):
    int* deg     = (int*)d_ws;                 // N
    int* row_ptr = deg + N_NODES;              // N+1
    int* cursor  = row_ptr + N_NODES + 1;      // N
    int* bsum    = cursor + N_NODES;           // 256
    int* boff    = bsum + 256;                 // 256
    int* perm    = boff + 256;                 // E
    size_t int_end = (size_t)(3 * N_NODES + 1 + 512) + N_EDGES;   // elements
    int_end = (int_end + 3) & ~(size_t)3;      // 16B align for float4
    float* agg = (float*)d_ws + int_end;       // N*D floats

    const int edge_blocks = (N_EDGES + 255) / 256;          // 1954
    const int scan_blocks = (N_NODES + 512) / 512;          // 196 (covers idx==N)
    const int gath_blocks = (N_NODES * 32) / 256;           // 12500
    const int gemm_blocks = N_NODES / 32;                   // 3125

    // ---- CSR build (graph identical for both layers) ----
    hipMemsetAsync(deg, 0, N_NODES * sizeof(int), stream);
    hist_kernel<<<edge_blocks, 256, 0, stream>>>(dst, deg);
    scanA_kernel<<<scan_blocks, 512, 0, stream>>>(deg, bsum);
    scanB_kernel<<<1, 256, 0, stream>>>(bsum, boff);
    scanC_kernel<<<scan_blocks, 512, 0, stream>>>(deg, boff, row_ptr, cursor);
    permute_kernel<<<edge_blocks, 256, 0, stream>>>(src, dst, cursor, perm);

    // ---- layer 1 (h lives in d_out) ----
    gather_kernel<<<gath_blocks, 256, 0, stream>>>(x, row_ptr, perm, agg);
    sage_gemm_kernel<<<gemm_blocks, 256, 0, stream>>>(x, agg, Wl1, bl1, Wr1,
                                                      out, /*relu=*/1);
    // ---- layer 2 (gather reads h=d_out fully before gemm overwrites it;
    //               gemm is in-place safe: each block reads only its own rows) ----
    gather_kernel<<<gath_blocks, 256, 0, stream>>>(out, row_ptr, perm, agg);
    sage_gemm_kernel<<<gemm_blocks, 256, 0, stream>>>(out, agg, Wl2, bl2, Wr2,
                                                      out, /*relu=*/0);
}

// Round 6
// 321.688 us; speedup vs baseline: 6.8411x; 2.2063x over previous
//
#include <hip/hip_runtime.h>
#include <cstddef>

#define N_NODES 100000
#define N_EDGES 500000
#define D 128  // D_IN = D_HID = D_OUT

typedef __attribute__((ext_vector_type(8))) short bf16x8;
typedef __attribute__((ext_vector_type(4))) float f32x4;

// round-to-nearest-even f32 -> bf16 (data is finite; no NaN handling)
static __device__ __forceinline__ short f2bf(float f)
{
    unsigned u = __builtin_bit_cast(unsigned, f);
    unsigned r = (u + 0x7fffu + ((u >> 16) & 1u)) >> 16;
    return (short)r;
}

// ---------------------------------------------------------------------------
// CSR build (per call, graph-capture-safe): counting sort of edges by dst.
// ---------------------------------------------------------------------------

__global__ __launch_bounds__(256)
void hist_kernel(const int* __restrict__ dst, int* __restrict__ deg)
{
    int e = blockIdx.x * 256 + threadIdx.x;
    if (e < N_EDGES) atomicAdd(&deg[dst[e]], 1);
}

__global__ __launch_bounds__(512)
void scanA_kernel(const int* __restrict__ deg, int* __restrict__ bsum)
{
    __shared__ int s[512];
    int t = threadIdx.x;
    int idx = blockIdx.x * 512 + t;
    s[t] = (idx < N_NODES) ? deg[idx] : 0;
    __syncthreads();
    for (int off = 256; off > 0; off >>= 1) {
        if (t < off) s[t] += s[t + off];
        __syncthreads();
    }
    if (t == 0) bsum[blockIdx.x] = s[0];
}

__global__ __launch_bounds__(256)
void scanB_kernel(const int* __restrict__ bsum, int* __restrict__ boff)
{
    __shared__ int s[256];
    int t = threadIdx.x;
    int v = (t < 196) ? bsum[t] : 0;
    s[t] = v;
    __syncthreads();
    for (int off = 1; off < 256; off <<= 1) {
        int a = s[t];
        if (t >= off) a += s[t - off];
        __syncthreads();
        s[t] = a;
        __syncthreads();
    }
    if (t < 196) boff[t] = s[t] - v;   // exclusive
}

__global__ __launch_bounds__(512)
void scanC_kernel(const int* __restrict__ deg, const int* __restrict__ boff,
                  int* __restrict__ row_ptr, int* __restrict__ cursor)
{
    __shared__ int s[512];
    int t = threadIdx.x;
    int idx = blockIdx.x * 512 + t;
    int v = (idx < N_NODES) ? deg[idx] : 0;
    s[t] = v;
    __syncthreads();
    for (int off = 1; off < 512; off <<= 1) {
        int a = s[t];
        if (t >= off) a += s[t - off];
        __syncthreads();
        s[t] = a;
        __syncthreads();
    }
    int excl = boff[blockIdx.x] + s[t] - v;
    if (idx < N_NODES) { row_ptr[idx] = excl; cursor[idx] = excl; }
    else if (idx == N_NODES) { row_ptr[idx] = excl; }
}

__global__ __launch_bounds__(256)
void permute_kernel(const int* __restrict__ src, const int* __restrict__ dst,
                    int* __restrict__ cursor, int* __restrict__ perm)
{
    int e = blockIdx.x * 256 + threadIdx.x;
    if (e < N_EDGES) {
        int pos = atomicAdd(&cursor[dst[e]], 1);
        perm[pos] = src[e];
    }
}

// ---------------------------------------------------------------------------
// Gather: agg[n][:] = (1/max(deg,1)) * sum_{e in CSR row n} x[perm[e]][:]
// 32 threads per node, one float4 per thread. fp32 output (pre-normalized).
// ---------------------------------------------------------------------------
__global__ __launch_bounds__(256)
void gather_kernel(const float* __restrict__ x,
                   const int* __restrict__ row_ptr,
                   const int* __restrict__ perm,
                   float* __restrict__ agg)
{
    unsigned gid = blockIdx.x * 256 + threadIdx.x;
    unsigned node = gid >> 5;
    unsigned c4 = (gid & 31) << 2;
    if (node >= N_NODES) return;
    int beg = row_ptr[node];
    int end = row_ptr[node + 1];
    float4 acc = make_float4(0.f, 0.f, 0.f, 0.f);
    int e = beg;
    for (; e + 4 <= end; e += 4) {
        int s0 = perm[e + 0], s1 = perm[e + 1], s2 = perm[e + 2], s3 = perm[e + 3];
        float4 v0 = *reinterpret_cast<const float4*>(x + (size_t)s0 * D + c4);
        float4 v1 = *reinterpret_cast<const float4*>(x + (size_t)s1 * D + c4);
        float4 v2 = *reinterpret_cast<const float4*>(x + (size_t)s2 * D + c4);
        float4 v3 = *reinterpret_cast<const float4*>(x + (size_t)s3 * D + c4);
        acc.x += (v0.x + v1.x) + (v2.x + v3.x);
        acc.y += (v0.y + v1.y) + (v2.y + v3.y);
        acc.z += (v0.z + v1.z) + (v2.z + v3.z);
        acc.w += (v0.w + v1.w) + (v2.w + v3.w);
    }
    for (; e < end; ++e) {
        int s0 = perm[e];
        float4 v0 = *reinterpret_cast<const float4*>(x + (size_t)s0 * D + c4);
        acc.x += v0.x; acc.y += v0.y; acc.z += v0.z; acc.w += v0.w;
    }
    float inv = 1.0f / fmaxf((float)(end - beg), 1.0f);
    acc.x *= inv; acc.y *= inv; acc.z *= inv; acc.w *= inv;
    *reinterpret_cast<float4*>(agg + (size_t)node * D + c4) = acc;
}

// ---------------------------------------------------------------------------
// Weight prep: pack Wcat = [Wl; Wr] (256x128 fp32) into bf16 MFMA-B fragments.
// blob[((ks*8+cb)*64+lane)*8+j] = bf16( Wcat[ks*32+(lane>>4)*8+j][cb*16+(lane&15)] )
// One thread per (frag,lane): 4096 threads.
// ---------------------------------------------------------------------------
__global__ __launch_bounds__(256)
void pack_w_kernel(const float* __restrict__ Wl, const float* __restrict__ Wr,
                   short* __restrict__ blob)
{
    int tid = blockIdx.x * 256 + threadIdx.x;   // 0..4095
    if (tid >= 4096) return;
    int lane = tid & 63;
    int frag = tid >> 6;        // 0..63 = ks*8+cb
    int cb = frag & 7;
    int ks = frag >> 3;
    int k0 = ks * 32 + (lane >> 4) * 8;         // global k row, multiple of 8
    int col = cb * 16 + (lane & 15);
    const float* W = (k0 < 128) ? (Wl + (size_t)k0 * D) : (Wr + (size_t)(k0 - 128) * D);
    bf16x8 v;
    #pragma unroll
    for (int j = 0; j < 8; ++j)
        v[j] = f2bf(W[(size_t)j * D + col]);
    *reinterpret_cast<bf16x8*>(blob + (size_t)tid * 8) = v;
}

// ---------------------------------------------------------------------------
// MFMA GEMM: out = act( agg @ Wl + self @ Wr + bias )   (Wcat = [Wl; Wr])
// Block: 64 rows, 4 waves; wave w owns rows 16w..16w+15 (reads & writes ONLY
// those rows -> in-place safe for out == self). 8 k-steps of 32; per step:
// lane loads 8 fp32 of its A-row, cvt->bf16x8, 8 MFMAs into acc[8].
// A frag: row=lane&15, k=(lane>>4)*8+j.  C/D: col=lane&15, row=(lane>>4)*4+r.
// ---------------------------------------------------------------------------
__global__ __launch_bounds__(256)
void mfma_gemm_kernel(const float* __restrict__ aggf,
                      const float* __restrict__ selff,
                      const short* __restrict__ blob,
                      const float* __restrict__ bias,
                      float* __restrict__ out,
                      int relu)
{
    const int tid = threadIdx.x;
    const int w = tid >> 6;
    const int lane = tid & 63;
    const int kch = lane >> 4;          // 0..3
    int row = blockIdx.x * 64 + w * 16 + (lane & 15);
    int rowc = row < N_NODES ? row : N_NODES - 1;   // clamp loads; garbage rows unstored

    const float* aggp = aggf + (size_t)rowc * D + kch * 8;
    const float* selfp = selff + (size_t)rowc * D + kch * 8;

    f32x4 acc[8] = {};

    #pragma unroll
    for (int ks = 0; ks < 8; ++ks) {
        // ks 0..3: agg rows (Wl half of Wcat); ks 4..7: self rows (Wr half)
        const float* src = (ks < 4) ? (aggp + ks * 32) : (selfp + (ks - 4) * 32);
        float4 lo = *reinterpret_cast<const float4*>(src);
        float4 hi = *reinterpret_cast<const float4*>(src + 4);
        bf16x8 a;
        a[0] = f2bf(lo.x); a[1] = f2bf(lo.y); a[2] = f2bf(lo.z); a[3] = f2bf(lo.w);
        a[4] = f2bf(hi.x); a[5] = f2bf(hi.y); a[6] = f2bf(hi.z); a[7] = f2bf(hi.w);
        const short* bptr = blob + ((size_t)(ks * 8) * 64 + lane) * 8;
        #pragma unroll
        for (int cb = 0; cb < 8; ++cb) {
            bf16x8 b = *reinterpret_cast<const bf16x8*>(bptr + (size_t)cb * 64 * 8);
            acc[cb] = __builtin_amdgcn_mfma_f32_16x16x32_bf16(a, b, acc[cb], 0, 0, 0);
        }
    }

    // epilogue: +bias, optional relu, guarded scalar stores
    const int colg = lane & 15;
    const int rbase = blockIdx.x * 64 + w * 16 + (lane >> 4) * 4;
    #pragma unroll
    for (int cb = 0; cb < 8; ++cb) {
        int col = cb * 16 + colg;
        float bv = bias[col];
        #pragma unroll
        for (int r = 0; r < 4; ++r) {
            int rr = rbase + r;
            if (rr < N_NODES) {
                float v = acc[cb][r] + bv;
                if (relu) v = fmaxf(v, 0.0f);
                out[(size_t)rr * D + col] = v;
            }
        }
    }
}

// ---------------------------------------------------------------------------
extern "C" void kernel_launch(void* const* d_in, const int* in_sizes, int n_in,
                              void* d_out, int out_size, void* d_ws, size_t ws_size,
                              hipStream_t stream)
{
    const float* x   = (const float*)d_in[0];
    const int*   ei  = (const int*)d_in[1];
    const int*   src = ei;              // edge_index[0]
    const int*   dst = ei + N_EDGES;    // edge_index[1]
    const float* Wl1 = (const float*)d_in[2];
    const float* bl1 = (const float*)d_in[3];
    const float* Wr1 = (const float*)d_in[4];
    const float* Wl2 = (const float*)d_in[5];
    const float* bl2 = (const float*)d_in[6];
    const float* Wr2 = (const float*)d_in[7];
    float* out = (float*)d_out;

    // workspace layout: ints | blob1,blob2 (bf16) | agg (fp32)
    int* deg     = (int*)d_ws;                 // N
    int* row_ptr = deg + N_NODES;              // N+1
    int* cursor  = row_ptr + N_NODES + 1;      // N
    int* bsum    = cursor + N_NODES;           // 256
    int* boff    = bsum + 256;                 // 256
    int* perm    = boff + 256;                 // E
    size_t int_end = (size_t)(3 * N_NODES + 1 + 512) + N_EDGES;   // int elements
    int_end = (int_end + 3) & ~(size_t)3;      // 16B align
    short* blob1 = (short*)((int*)d_ws + int_end);   // 4096*8 shorts = 64KB
    short* blob2 = blob1 + 32768;                    // 64KB
    float* agg   = (float*)(blob2 + 32768);          // N*D fp32 (16B-aligned)

    const int edge_blocks = (N_EDGES + 255) / 256;          // 1954
    const int scan_blocks = (N_NODES + 512) / 512;          // 196 (covers idx==N)
    const int gath_blocks = (N_NODES * 32) / 256;           // 12500
    const int gemm_blocks = (N_NODES + 63) / 64;            // 1563

    // ---- CSR build + weight packing (graph/weights same for whole call) ----
    hipMemsetAsync(deg, 0, N_NODES * sizeof(int), stream);
    hist_kernel<<<edge_blocks, 256, 0, stream>>>(dst, deg);
    scanA_kernel<<<scan_blocks, 512, 0, stream>>>(deg, bsum);
    scanB_kernel<<<1, 256, 0, stream>>>(bsum, boff);
    scanC_kernel<<<scan_blocks, 512, 0, stream>>>(deg, boff, row_ptr, cursor);
    permute_kernel<<<edge_blocks, 256, 0, stream>>>(src, dst, cursor, perm);
    pack_w_kernel<<<16, 256, 0, stream>>>(Wl1, Wr1, blob1);
    pack_w_kernel<<<16, 256, 0, stream>>>(Wl2, Wr2, blob2);

    // ---- layer 1: h = relu(agg@Wl1 + b + x@Wr1), h lives in d_out ----
    gather_kernel<<<gath_blocks, 256, 0, stream>>>(x, row_ptr, perm, agg);
    mfma_gemm_kernel<<<gemm_blocks, 256, 0, stream>>>(agg, x, blob1, bl1, out, 1);

    // ---- layer 2: out = agg2@Wl2 + b + h@Wr2 (gather2 reads h fully before
    //      gemm2; gemm2 in-place safe: each wave reads only its own rows) ----
    gather_kernel<<<gath_blocks, 256, 0, stream>>>(out, row_ptr, perm, agg);
    mfma_gemm_kernel<<<gemm_blocks, 256, 0, stream>>>(agg, out, blob2, bl2, out, 0);
}

// Round 8
// 296.071 us; speedup vs baseline: 7.4330x; 1.0865x over previous
//
#include <hip/hip_runtime.h>
#include <cstddef>

#define N_NODES 100000
#define N_EDGES 500000
#define D 128  // D_IN = D_HID = D_OUT

typedef __attribute__((ext_vector_type(8))) short bf16x8;
typedef __attribute__((ext_vector_type(4))) float f32x4;

// round-to-nearest-even f32 -> bf16 (data is finite; no NaN handling)
static __device__ __forceinline__ short f2bf(float f)
{
    unsigned u = __builtin_bit_cast(unsigned, f);
    unsigned r = (u + 0x7fffu + ((u >> 16) & 1u)) >> 16;
    return (short)r;
}
static __device__ __forceinline__ float b2f(short s)
{
    return __builtin_bit_cast(float, (unsigned)((unsigned short)s) << 16);
}

// ---------------------------------------------------------------------------
// CSR build (per call, graph-capture-safe): counting sort of edges by dst.
// ---------------------------------------------------------------------------

__global__ __launch_bounds__(256)
void hist_kernel(const int* __restrict__ dst, int* __restrict__ deg)
{
    int e = blockIdx.x * 256 + threadIdx.x;
    if (e < N_EDGES) atomicAdd(&deg[dst[e]], 1);
}

__global__ __launch_bounds__(512)
void scanA_kernel(const int* __restrict__ deg, int* __restrict__ bsum)
{
    __shared__ int s[512];
    int t = threadIdx.x;
    int idx = blockIdx.x * 512 + t;
    s[t] = (idx < N_NODES) ? deg[idx] : 0;
    __syncthreads();
    for (int off = 256; off > 0; off >>= 1) {
        if (t < off) s[t] += s[t + off];
        __syncthreads();
    }
    if (t == 0) bsum[blockIdx.x] = s[0];
}

__global__ __launch_bounds__(256)
void scanB_kernel(const int* __restrict__ bsum, int* __restrict__ boff)
{
    __shared__ int s[256];
    int t = threadIdx.x;
    int v = (t < 196) ? bsum[t] : 0;
    s[t] = v;
    __syncthreads();
    for (int off = 1; off < 256; off <<= 1) {
        int a = s[t];
        if (t >= off) a += s[t - off];
        __syncthreads();
        s[t] = a;
        __syncthreads();
    }
    if (t < 196) boff[t] = s[t] - v;   // exclusive
}

__global__ __launch_bounds__(512)
void scanC_kernel(const int* __restrict__ deg, const int* __restrict__ boff,
                  int* __restrict__ row_ptr, int* __restrict__ cursor)
{
    __shared__ int s[512];
    int t = threadIdx.x;
    int idx = blockIdx.x * 512 + t;
    int v = (idx < N_NODES) ? deg[idx] : 0;
    s[t] = v;
    __syncthreads();
    for (int off = 1; off < 512; off <<= 1) {
        int a = s[t];
        if (t >= off) a += s[t - off];
        __syncthreads();
        s[t] = a;
        __syncthreads();
    }
    int excl = boff[blockIdx.x] + s[t] - v;
    if (idx < N_NODES) { row_ptr[idx] = excl; cursor[idx] = excl; }
    else if (idx == N_NODES) { row_ptr[idx] = excl; }
}

__global__ __launch_bounds__(256)
void permute_kernel(const int* __restrict__ src, const int* __restrict__ dst,
                    int* __restrict__ cursor, int* __restrict__ perm)
{
    int e = blockIdx.x * 256 + threadIdx.x;
    if (e < N_EDGES) {
        int pos = atomicAdd(&cursor[dst[e]], 1);
        perm[pos] = src[e];
    }
}

// ---------------------------------------------------------------------------
// Cast x (fp32) -> xb (bf16), 8 elems/thread.
// ---------------------------------------------------------------------------
__global__ __launch_bounds__(256)
void cast_kernel(const float* __restrict__ in, short* __restrict__ outb)
{
    int i = blockIdx.x * 256 + threadIdx.x;     // < N*D/8 = 1.6M exactly
    const float4* p = reinterpret_cast<const float4*>(in) + (size_t)i * 2;
    float4 lo = p[0], hi = p[1];
    bf16x8 v;
    v[0] = f2bf(lo.x); v[1] = f2bf(lo.y); v[2] = f2bf(lo.z); v[3] = f2bf(lo.w);
    v[4] = f2bf(hi.x); v[5] = f2bf(hi.y); v[6] = f2bf(hi.z); v[7] = f2bf(hi.w);
    *reinterpret_cast<bf16x8*>(outb + (size_t)i * 8) = v;
}

// ---------------------------------------------------------------------------
// Gather (bf16): aggb[n][:] = bf16( (1/max(deg,1)) * sum x[perm[e]][:] )
// 16 lanes/node, 8 bf16 (16B) per lane per edge; fp32 accumulation.
// ---------------------------------------------------------------------------
__global__ __launch_bounds__(256)
void gather_kernel(const short* __restrict__ xb,
                   const int* __restrict__ row_ptr,
                   const int* __restrict__ perm,
                   short* __restrict__ aggb)
{
    unsigned gid = blockIdx.x * 256 + threadIdx.x;
    unsigned node = gid >> 4;           // 6250 blocks * 16 nodes = 100000 exact
    unsigned c8 = (gid & 15) << 3;      // elem offset 0..120
    if (node >= N_NODES) return;
    int beg = row_ptr[node];
    int end = row_ptr[node + 1];
    float acc[8] = {};
    int e = beg;
    for (; e + 2 <= end; e += 2) {
        int s0 = perm[e], s1 = perm[e + 1];
        bf16x8 v0 = *reinterpret_cast<const bf16x8*>(xb + (size_t)s0 * D + c8);
        bf16x8 v1 = *reinterpret_cast<const bf16x8*>(xb + (size_t)s1 * D + c8);
        #pragma unroll
        for (int j = 0; j < 8; ++j) acc[j] += b2f(v0[j]) + b2f(v1[j]);
    }
    if (e < end) {
        int s0 = perm[e];
        bf16x8 v0 = *reinterpret_cast<const bf16x8*>(xb + (size_t)s0 * D + c8);
        #pragma unroll
        for (int j = 0; j < 8; ++j) acc[j] += b2f(v0[j]);
    }
    float inv = 1.0f / fmaxf((float)(end - beg), 1.0f);
    bf16x8 o;
    #pragma unroll
    for (int j = 0; j < 8; ++j) o[j] = f2bf(acc[j] * inv);
    *reinterpret_cast<bf16x8*>(aggb + (size_t)node * D + c8) = o;
}

// ---------------------------------------------------------------------------
// Weight prep: pack [Wl1;Wr1] and [Wl2;Wr2] into bf16 MFMA-B fragment blobs.
// blob[((ks*8+cb)*64+lane)*8+j] = bf16( Wcat[ks*32+(lane>>4)*8+j][cb*16+(lane&15)] )
// tid 0..4095 -> blob1, 4096..8191 -> blob2.
// ---------------------------------------------------------------------------
__global__ __launch_bounds__(256)
void pack_w_kernel(const float* __restrict__ Wl1, const float* __restrict__ Wr1,
                   const float* __restrict__ Wl2, const float* __restrict__ Wr2,
                   short* __restrict__ blob)       // blob1 | blob2 contiguous
{
    int tid = blockIdx.x * 256 + threadIdx.x;   // 0..8191
    if (tid >= 8192) return;
    int lane = tid & 63;
    int frag = (tid >> 6) & 63;  // ks*8+cb
    int layer = tid >> 12;       // 0 or 1
    int cb = frag & 7;
    int ks = frag >> 3;
    int k0 = ks * 32 + (lane >> 4) * 8;
    int col = cb * 16 + (lane & 15);
    const float* Wl = layer ? Wl2 : Wl1;
    const float* Wr = layer ? Wr2 : Wr1;
    const float* W = (k0 < 128) ? (Wl + (size_t)k0 * D) : (Wr + (size_t)(k0 - 128) * D);
    bf16x8 v;
    #pragma unroll
    for (int j = 0; j < 8; ++j)
        v[j] = f2bf(W[(size_t)j * D + col]);
    *reinterpret_cast<bf16x8*>(blob + (size_t)tid * 8) = v;
}

// ---------------------------------------------------------------------------
// MFMA GEMM: acc = agg @ Wl + self @ Wr  (Wcat = [Wl; Wr], A inputs bf16)
// Block: 64 rows, 4 waves; wave w owns rows 16w..16w+15 (reads & writes ONLY
// those rows). mode 1: h = bf16(relu(acc+bias)) -> outb (may alias selfb:
// every store is data-dependent on all of this wave's self loads, and waves
// touch only their own rows -> in-place safe). mode 0: fp32 acc+bias -> outf.
// A frag: row=lane&15, k=(lane>>4)*8+j.  C/D: col=lane&15, row=(lane>>4)*4+r.
// ---------------------------------------------------------------------------
__global__ __launch_bounds__(256)
void mfma_gemm_kernel(const short* __restrict__ aggb,
                      const short* __restrict__ selfb,
                      const short* __restrict__ blob,
                      const float* __restrict__ bias,
                      float* __restrict__ outf,
                      short* __restrict__ outb,
                      int mode)
{
    const int tid = threadIdx.x;
    const int w = tid >> 6;
    const int lane = tid & 63;
    const int kch = lane >> 4;          // 0..3
    int row = blockIdx.x * 64 + w * 16 + (lane & 15);
    int rowc = row < N_NODES ? row : N_NODES - 1;   // clamp loads; garbage rows unstored

    const short* aggp = aggb + (size_t)rowc * D + kch * 8;
    const short* selfp = selfb + (size_t)rowc * D + kch * 8;

    f32x4 acc[8] = {};

    #pragma unroll
    for (int ks = 0; ks < 8; ++ks) {
        // ks 0..3: agg rows (Wl half of Wcat); ks 4..7: self rows (Wr half)
        const short* src = (ks < 4) ? (aggp + ks * 32) : (selfp + (ks - 4) * 32);
        bf16x8 a = *reinterpret_cast<const bf16x8*>(src);
        const short* bptr = blob + ((size_t)(ks * 8) * 64 + lane) * 8;
        #pragma unroll
        for (int cb = 0; cb < 8; ++cb) {
            bf16x8 b = *reinterpret_cast<const bf16x8*>(bptr + (size_t)cb * 64 * 8);
            acc[cb] = __builtin_amdgcn_mfma_f32_16x16x32_bf16(a, b, acc[cb], 0, 0, 0);
        }
    }

    // epilogue
    const int colg = lane & 15;
    const int rbase = blockIdx.x * 64 + w * 16 + (lane >> 4) * 4;
    #pragma unroll
    for (int cb = 0; cb < 8; ++cb) {
        int col = cb * 16 + colg;
        float bv = bias[col];
        #pragma unroll
        for (int r = 0; r < 4; ++r) {
            int rr = rbase + r;
            if (rr < N_NODES) {
                float v = acc[cb][r] + bv;
                if (mode) {
                    v = fmaxf(v, 0.0f);
                    outb[(size_t)rr * D + col] = f2bf(v);
                } else {
                    outf[(size_t)rr * D + col] = v;
                }
            }
        }
    }
}

// ---------------------------------------------------------------------------
extern "C" void kernel_launch(void* const* d_in, const int* in_sizes, int n_in,
                              void* d_out, int out_size, void* d_ws, size_t ws_size,
                              hipStream_t stream)
{
    const float* x   = (const float*)d_in[0];
    const int*   ei  = (const int*)d_in[1];
    const int*   src = ei;              // edge_index[0]
    const int*   dst = ei + N_EDGES;    // edge_index[1]
    const float* Wl1 = (const float*)d_in[2];
    const float* bl1 = (const float*)d_in[3];
    const float* Wr1 = (const float*)d_in[4];
    const float* Wl2 = (const float*)d_in[5];
    const float* bl2 = (const float*)d_in[6];
    const float* Wr2 = (const float*)d_in[7];
    float* out = (float*)d_out;

    // workspace: ints | blob1,blob2 | xb (=hb, bf16) | aggb (bf16)  ~54 MB
    int* deg     = (int*)d_ws;                 // N
    int* row_ptr = deg + N_NODES;              // N+1
    int* cursor  = row_ptr + N_NODES + 1;      // N
    int* bsum    = cursor + N_NODES;           // 256
    int* boff    = bsum + 256;                 // 256
    int* perm    = boff + 256;                 // E
    size_t int_end = (size_t)(3 * N_NODES + 1 + 512) + N_EDGES;   // int elements
    int_end = (int_end + 3) & ~(size_t)3;      // 16B align
    short* blob1 = (short*)((int*)d_ws + int_end);   // 4096*8 shorts
    short* blob2 = blob1 + 32768;
    short* xb    = blob2 + 32768;                    // N*D bf16; h overwrites in place
    short* aggb  = xb + (size_t)N_NODES * D;         // N*D bf16

    const int edge_blocks = (N_EDGES + 255) / 256;          // 1954
    const int scan_blocks = (N_NODES + 512) / 512;          // 196 (covers idx==N)
    const int cast_blocks = (N_NODES * D / 8) / 256;        // 6250
    const int gath_blocks = (N_NODES * 16) / 256;           // 6250
    const int gemm_blocks = (N_NODES + 63) / 64;            // 1563

    // ---- CSR build + x cast + weight packing ----
    hipMemsetAsync(deg, 0, N_NODES * sizeof(int), stream);
    hist_kernel<<<edge_blocks, 256, 0, stream>>>(dst, deg);
    scanA_kernel<<<scan_blocks, 512, 0, stream>>>(deg, bsum);
    scanB_kernel<<<1, 256, 0, stream>>>(bsum, boff);
    scanC_kernel<<<scan_blocks, 512, 0, stream>>>(deg, boff, row_ptr, cursor);
    permute_kernel<<<edge_blocks, 256, 0, stream>>>(src, dst, cursor, perm);
    cast_kernel<<<cast_blocks, 256, 0, stream>>>(x, xb);
    pack_w_kernel<<<32, 256, 0, stream>>>(Wl1, Wr1, Wl2, Wr2, blob1);

    // ---- layer 1: h = bf16(relu(agg@Wl1 + b + x@Wr1)), h overwrites xb ----
    gather_kernel<<<gath_blocks, 256, 0, stream>>>(xb, row_ptr, perm, aggb);
    mfma_gemm_kernel<<<gemm_blocks, 256, 0, stream>>>(aggb, xb, blob1, bl1,
                                                      nullptr, xb, 1);

    // ---- layer 2: out = agg2@Wl2 + b + h@Wr2 (fp32 to d_out) ----
    gather_kernel<<<gath_blocks, 256, 0, stream>>>(xb, row_ptr, perm, aggb);
    mfma_gemm_kernel<<<gemm_blocks, 256, 0, stream>>>(aggb, xb, blob2, bl2,
                                                      out, nullptr, 0);
}

// Round 9
// 293.396 us; speedup vs baseline: 7.5008x; 1.0091x over previous
//
#include <hip/hip_runtime.h>
#include <cstddef>

#define N_NODES 100000
#define N_EDGES 500000
#define D 128  // D_IN = D_HID = D_OUT

typedef __attribute__((ext_vector_type(8))) short bf16x8;
typedef __attribute__((ext_vector_type(4))) float f32x4;

// round-to-nearest-even f32 -> bf16 (data is finite; no NaN handling)
static __device__ __forceinline__ short f2bf(float f)
{
    unsigned u = __builtin_bit_cast(unsigned, f);
    unsigned r = (u + 0x7fffu + ((u >> 16) & 1u)) >> 16;
    return (short)r;
}
static __device__ __forceinline__ float b2f(short s)
{
    return __builtin_bit_cast(float, (unsigned)((unsigned short)s) << 16);
}

// ---------------------------------------------------------------------------
// CSR build (per call, graph-capture-safe): counting sort of edges by dst.
// ---------------------------------------------------------------------------

__global__ __launch_bounds__(256)
void hist_kernel(const int* __restrict__ dst, int* __restrict__ deg)
{
    int e = blockIdx.x * 256 + threadIdx.x;
    if (e < N_EDGES) atomicAdd(&deg[dst[e]], 1);
}

__global__ __launch_bounds__(512)
void scanA_kernel(const int* __restrict__ deg, int* __restrict__ bsum)
{
    __shared__ int s[512];
    int t = threadIdx.x;
    int idx = blockIdx.x * 512 + t;
    s[t] = (idx < N_NODES) ? deg[idx] : 0;
    __syncthreads();
    for (int off = 256; off > 0; off >>= 1) {
        if (t < off) s[t] += s[t + off];
        __syncthreads();
    }
    if (t == 0) bsum[blockIdx.x] = s[0];
}

__global__ __launch_bounds__(256)
void scanB_kernel(const int* __restrict__ bsum, int* __restrict__ boff)
{
    __shared__ int s[256];
    int t = threadIdx.x;
    int v = (t < 196) ? bsum[t] : 0;
    s[t] = v;
    __syncthreads();
    for (int off = 1; off < 256; off <<= 1) {
        int a = s[t];
        if (t >= off) a += s[t - off];
        __syncthreads();
        s[t] = a;
        __syncthreads();
    }
    if (t < 196) boff[t] = s[t] - v;   // exclusive
}

__global__ __launch_bounds__(512)
void scanC_kernel(const int* __restrict__ deg, const int* __restrict__ boff,
                  int* __restrict__ row_ptr, int* __restrict__ cursor)
{
    __shared__ int s[512];
    int t = threadIdx.x;
    int idx = blockIdx.x * 512 + t;
    int v = (idx < N_NODES) ? deg[idx] : 0;
    s[t] = v;
    __syncthreads();
    for (int off = 1; off < 512; off <<= 1) {
        int a = s[t];
        if (t >= off) a += s[t - off];
        __syncthreads();
        s[t] = a;
        __syncthreads();
    }
    int excl = boff[blockIdx.x] + s[t] - v;
    if (idx < N_NODES) { row_ptr[idx] = excl; cursor[idx] = excl; }
    else if (idx == N_NODES) { row_ptr[idx] = excl; }
}

__global__ __launch_bounds__(256)
void permute_kernel(const int* __restrict__ src, const int* __restrict__ dst,
                    int* __restrict__ cursor, int* __restrict__ perm)
{
    int e = blockIdx.x * 256 + threadIdx.x;
    if (e < N_EDGES) {
        int pos = atomicAdd(&cursor[dst[e]], 1);
        perm[pos] = src[e];
    }
}

// ---------------------------------------------------------------------------
// Cast x (fp32) -> xb (bf16), 8 elems/thread.
// ---------------------------------------------------------------------------
__global__ __launch_bounds__(256)
void cast_kernel(const float* __restrict__ in, short* __restrict__ outb)
{
    int i = blockIdx.x * 256 + threadIdx.x;     // < N*D/8 = 1.6M exactly
    const float4* p = reinterpret_cast<const float4*>(in) + (size_t)i * 2;
    float4 lo = p[0], hi = p[1];
    bf16x8 v;
    v[0] = f2bf(lo.x); v[1] = f2bf(lo.y); v[2] = f2bf(lo.z); v[3] = f2bf(lo.w);
    v[4] = f2bf(hi.x); v[5] = f2bf(hi.y); v[6] = f2bf(hi.z); v[7] = f2bf(hi.w);
    *reinterpret_cast<bf16x8*>(outb + (size_t)i * 8) = v;
}

// ---------------------------------------------------------------------------
// Weight prep: pack [Wl1;Wr1] and [Wl2;Wr2] into bf16 MFMA-B fragment blobs.
// blob[((ks*8+cb)*64+lane)*8+j] = bf16( Wcat[ks*32+(lane>>4)*8+j][cb*16+(lane&15)] )
// tid 0..4095 -> blob1, 4096..8191 -> blob2.
// ---------------------------------------------------------------------------
__global__ __launch_bounds__(256)
void pack_w_kernel(const float* __restrict__ Wl1, const float* __restrict__ Wr1,
                   const float* __restrict__ Wl2, const float* __restrict__ Wr2,
                   short* __restrict__ blob)       // blob1 | blob2 contiguous
{
    int tid = blockIdx.x * 256 + threadIdx.x;   // 0..8191
    if (tid >= 8192) return;
    int lane = tid & 63;
    int frag = (tid >> 6) & 63;  // ks*8+cb
    int layer = tid >> 12;       // 0 or 1
    int cb = frag & 7;
    int ks = frag >> 3;
    int k0 = ks * 32 + (lane >> 4) * 8;
    int col = cb * 16 + (lane & 15);
    const float* Wl = layer ? Wl2 : Wl1;
    const float* Wr = layer ? Wr2 : Wr1;
    const float* W = (k0 < 128) ? (Wl + (size_t)k0 * D) : (Wr + (size_t)(k0 - 128) * D);
    bf16x8 v;
    #pragma unroll
    for (int j = 0; j < 8; ++j)
        v[j] = f2bf(W[(size_t)j * D + col]);
    *reinterpret_cast<bf16x8*>(blob + (size_t)tid * 8) = v;
}

// ---------------------------------------------------------------------------
// Fused layer: per block of 64 output rows:
//   phase 1: gather agg tile (64x128 bf16) into LDS, XOR-swizzled
//            (16 lanes/node, fp32 accum, /deg, bf16 round — same numerics
//             as the standalone gather path)
//   phase 2: MFMA acc = agg @ Wl + self @ Wr; epilogue +bias [+relu].
// mode 1: outb = bf16(relu(acc+bias))   (separate buffer, no aliasing)
// mode 0: outf = fp32(acc+bias)
// LDS swizzle: short-index ^= (row&7)<<3 on BOTH write and read (same
// involution both sides; breaks the 16-rows-same-column bank collision).
// A frag: row=lane&15, k=(lane>>4)*8+j.  C/D: col=lane&15, row=(lane>>4)*4+r.
// ---------------------------------------------------------------------------
__global__ __launch_bounds__(256)
void fused_layer_kernel(const short* __restrict__ gsrc,   // gather source rows
                        const short* __restrict__ selfb,  // self rows (same buf)
                        const int* __restrict__ row_ptr,
                        const int* __restrict__ perm,
                        const short* __restrict__ blob,
                        const float* __restrict__ bias,
                        float* __restrict__ outf,
                        short* __restrict__ outb,
                        int mode)
{
    __shared__ short As[64 * 128];   // 16 KB agg tile (swizzled)

    const int tid = threadIdx.x;
    const int row0 = blockIdx.x * 64;

    // ---- phase 1: gather ----
    {
        const int c8 = (tid & 15) * 8;          // col offset in shorts
        for (int p = 0; p < 4; ++p) {
            int r = p * 16 + (tid >> 4);        // 0..63
            int node = row0 + r;
            if (node < N_NODES) {
                int beg = row_ptr[node];
                int end = row_ptr[node + 1];
                float acc[8] = {};
                int e = beg;
                for (; e + 2 <= end; e += 2) {
                    int s0 = perm[e], s1 = perm[e + 1];
                    bf16x8 v0 = *reinterpret_cast<const bf16x8*>(gsrc + (size_t)s0 * D + c8);
                    bf16x8 v1 = *reinterpret_cast<const bf16x8*>(gsrc + (size_t)s1 * D + c8);
                    #pragma unroll
                    for (int j = 0; j < 8; ++j) acc[j] += b2f(v0[j]) + b2f(v1[j]);
                }
                if (e < end) {
                    int s0 = perm[e];
                    bf16x8 v0 = *reinterpret_cast<const bf16x8*>(gsrc + (size_t)s0 * D + c8);
                    #pragma unroll
                    for (int j = 0; j < 8; ++j) acc[j] += b2f(v0[j]);
                }
                float inv = 1.0f / fmaxf((float)(end - beg), 1.0f);
                bf16x8 o;
                #pragma unroll
                for (int j = 0; j < 8; ++j) o[j] = f2bf(acc[j] * inv);
                int idx = (r * 128 + c8) ^ ((r & 7) << 3);
                *reinterpret_cast<bf16x8*>(As + idx) = o;
            }
        }
    }
    __syncthreads();

    // ---- phase 2: MFMA ----
    const int w = tid >> 6;
    const int lane = tid & 63;
    const int kch = lane >> 4;          // 0..3
    const int rloc = w * 16 + (lane & 15);
    int row = row0 + rloc;
    int rowc = row < N_NODES ? row : N_NODES - 1;   // clamp loads; garbage unstored

    const short* selfp = selfb + (size_t)rowc * D + kch * 8;

    f32x4 acc[8] = {};

    #pragma unroll
    for (int ks = 0; ks < 8; ++ks) {
        bf16x8 a;
        if (ks < 4) {
            // agg half from LDS (swizzled read, same XOR as write)
            int idx = (rloc * 128 + ks * 32 + kch * 8) ^ ((rloc & 7) << 3);
            a = *reinterpret_cast<const bf16x8*>(As + idx);
        } else {
            a = *reinterpret_cast<const bf16x8*>(selfp + (ks - 4) * 32);
        }
        const short* bptr = blob + ((size_t)(ks * 8) * 64 + lane) * 8;
        #pragma unroll
        for (int cb = 0; cb < 8; ++cb) {
            bf16x8 b = *reinterpret_cast<const bf16x8*>(bptr + (size_t)cb * 64 * 8);
            acc[cb] = __builtin_amdgcn_mfma_f32_16x16x32_bf16(a, b, acc[cb], 0, 0, 0);
        }
    }

    // ---- epilogue ----
    const int colg = lane & 15;
    const int rbase = row0 + w * 16 + (lane >> 4) * 4;
    #pragma unroll
    for (int cb = 0; cb < 8; ++cb) {
        int col = cb * 16 + colg;
        float bv = bias[col];
        #pragma unroll
        for (int r = 0; r < 4; ++r) {
            int rr = rbase + r;
            if (rr < N_NODES) {
                float v = acc[cb][r] + bv;
                if (mode) {
                    v = fmaxf(v, 0.0f);
                    outb[(size_t)rr * D + col] = f2bf(v);
                } else {
                    outf[(size_t)rr * D + col] = v;
                }
            }
        }
    }
}

// ---------------------------------------------------------------------------
extern "C" void kernel_launch(void* const* d_in, const int* in_sizes, int n_in,
                              void* d_out, int out_size, void* d_ws, size_t ws_size,
                              hipStream_t stream)
{
    const float* x   = (const float*)d_in[0];
    const int*   ei  = (const int*)d_in[1];
    const int*   src = ei;              // edge_index[0]
    const int*   dst = ei + N_EDGES;    // edge_index[1]
    const float* Wl1 = (const float*)d_in[2];
    const float* bl1 = (const float*)d_in[3];
    const float* Wr1 = (const float*)d_in[4];
    const float* Wl2 = (const float*)d_in[5];
    const float* bl2 = (const float*)d_in[6];
    const float* Wr2 = (const float*)d_in[7];
    float* out = (float*)d_out;

    // workspace: ints | blob1,blob2 | xb (bf16) | hb (bf16)   ~54 MB
    int* deg     = (int*)d_ws;                 // N
    int* row_ptr = deg + N_NODES;              // N+1
    int* cursor  = row_ptr + N_NODES + 1;      // N
    int* bsum    = cursor + N_NODES;           // 256
    int* boff    = bsum + 256;                 // 256
    int* perm    = boff + 256;                 // E
    size_t int_end = (size_t)(3 * N_NODES + 1 + 512) + N_EDGES;   // int elements
    int_end = (int_end + 3) & ~(size_t)3;      // 16B align
    short* blob1 = (short*)((int*)d_ws + int_end);   // 4096*8 shorts
    short* blob2 = blob1 + 32768;
    short* xb    = blob2 + 32768;                    // N*D bf16
    short* hb    = xb + (size_t)N_NODES * D;         // N*D bf16 (layer-1 output)

    const int edge_blocks = (N_EDGES + 255) / 256;          // 1954
    const int scan_blocks = (N_NODES + 512) / 512;          // 196 (covers idx==N)
    const int cast_blocks = (N_NODES * D / 8) / 256;        // 6250
    const int fuse_blocks = (N_NODES + 63) / 64;            // 1563

    // ---- CSR build + x cast + weight packing ----
    hipMemsetAsync(deg, 0, N_NODES * sizeof(int), stream);
    hist_kernel<<<edge_blocks, 256, 0, stream>>>(dst, deg);
    scanA_kernel<<<scan_blocks, 512, 0, stream>>>(deg, bsum);
    scanB_kernel<<<1, 256, 0, stream>>>(bsum, boff);
    scanC_kernel<<<scan_blocks, 512, 0, stream>>>(deg, boff, row_ptr, cursor);
    permute_kernel<<<edge_blocks, 256, 0, stream>>>(src, dst, cursor, perm);
    cast_kernel<<<cast_blocks, 256, 0, stream>>>(x, xb);
    pack_w_kernel<<<32, 256, 0, stream>>>(Wl1, Wr1, Wl2, Wr2, blob1);

    // ---- layer 1: hb = bf16(relu(agg(xb)@Wl1 + b + xb@Wr1)) ----
    fused_layer_kernel<<<fuse_blocks, 256, 0, stream>>>(xb, xb, row_ptr, perm,
                                                        blob1, bl1, nullptr, hb, 1);

    // ---- layer 2: out = agg(hb)@Wl2 + b + hb@Wr2 (fp32) ----
    fused_layer_kernel<<<fuse_blocks, 256, 0, stream>>>(hb, hb, row_ptr, perm,
                                                        blob2, bl2, out, nullptr, 0);
}

// Round 10
// 288.017 us; speedup vs baseline: 7.6409x; 1.0187x over previous
//
#include <hip/hip_runtime.h>
#include <cstddef>

#define N_NODES 100000
#define N_EDGES 500000
#define D 128  // D_IN = D_HID = D_OUT

typedef __attribute__((ext_vector_type(8))) short bf16x8;
typedef __attribute__((ext_vector_type(4))) float f32x4;

// round-to-nearest-even f32 -> bf16 (data is finite; no NaN handling)
static __device__ __forceinline__ short f2bf(float f)
{
    unsigned u = __builtin_bit_cast(unsigned, f);
    unsigned r = (u + 0x7fffu + ((u >> 16) & 1u)) >> 16;
    return (short)r;
}
static __device__ __forceinline__ float b2f(short s)
{
    return __builtin_bit_cast(float, (unsigned)((unsigned short)s) << 16);
}

// ---------------------------------------------------------------------------
// CSR build (per call, graph-capture-safe): counting sort of edges by dst.
// ---------------------------------------------------------------------------

// prep: cast x->xb (all 1.6M threads), dst histogram (gid<E), pack weights
// (gid<8192). Merged to cut dispatch count; the three jobs are independent.
__global__ __launch_bounds__(256)
void prep_kernel(const float* __restrict__ x, short* __restrict__ xb,
                 const int* __restrict__ dst, int* __restrict__ deg,
                 const float* __restrict__ Wl1, const float* __restrict__ Wr1,
                 const float* __restrict__ Wl2, const float* __restrict__ Wr2,
                 short* __restrict__ blob)
{
    int gid = blockIdx.x * 256 + threadIdx.x;   // < N*D/8 = 1.6M exactly

    // ---- cast: 8 elems/thread ----
    {
        const float4* p = reinterpret_cast<const float4*>(x) + (size_t)gid * 2;
        float4 lo = p[0], hi = p[1];
        bf16x8 v;
        v[0] = f2bf(lo.x); v[1] = f2bf(lo.y); v[2] = f2bf(lo.z); v[3] = f2bf(lo.w);
        v[4] = f2bf(hi.x); v[5] = f2bf(hi.y); v[6] = f2bf(hi.z); v[7] = f2bf(hi.w);
        *reinterpret_cast<bf16x8*>(xb + (size_t)gid * 8) = v;
    }

    // ---- histogram ----
    if (gid < N_EDGES) atomicAdd(&deg[dst[gid]], 1);

    // ---- weight pack: blob[((ks*8+cb)*64+lane)*8+j] =
    //      bf16( Wcat[ks*32+(lane>>4)*8+j][cb*16+(lane&15)] ), 2 layers ----
    if (gid < 8192) {
        int lane = gid & 63;
        int frag = (gid >> 6) & 63;  // ks*8+cb
        int layer = gid >> 12;       // 0 or 1
        int cb = frag & 7;
        int ks = frag >> 3;
        int k0 = ks * 32 + (lane >> 4) * 8;
        int col = cb * 16 + (lane & 15);
        const float* Wl = layer ? Wl2 : Wl1;
        const float* Wr = layer ? Wr2 : Wr1;
        const float* W = (k0 < 128) ? (Wl + (size_t)k0 * D)
                                    : (Wr + (size_t)(k0 - 128) * D);
        bf16x8 v;
        #pragma unroll
        for (int j = 0; j < 8; ++j)
            v[j] = f2bf(W[(size_t)j * D + col]);
        *reinterpret_cast<bf16x8*>(blob + (size_t)gid * 8) = v;
    }
}

__global__ __launch_bounds__(512)
void scanA_kernel(const int* __restrict__ deg, int* __restrict__ bsum)
{
    __shared__ int s[512];
    int t = threadIdx.x;
    int idx = blockIdx.x * 512 + t;
    s[t] = (idx < N_NODES) ? deg[idx] : 0;
    __syncthreads();
    for (int off = 256; off > 0; off >>= 1) {
        if (t < off) s[t] += s[t + off];
        __syncthreads();
    }
    if (t == 0) bsum[blockIdx.x] = s[0];
}

__global__ __launch_bounds__(256)
void scanB_kernel(const int* __restrict__ bsum, int* __restrict__ boff)
{
    __shared__ int s[256];
    int t = threadIdx.x;
    int v = (t < 196) ? bsum[t] : 0;
    s[t] = v;
    __syncthreads();
    for (int off = 1; off < 256; off <<= 1) {
        int a = s[t];
        if (t >= off) a += s[t - off];
        __syncthreads();
        s[t] = a;
        __syncthreads();
    }
    if (t < 196) boff[t] = s[t] - v;   // exclusive
}

__global__ __launch_bounds__(512)
void scanC_kernel(const int* __restrict__ deg, const int* __restrict__ boff,
                  int* __restrict__ row_ptr, int* __restrict__ cursor)
{
    __shared__ int s[512];
    int t = threadIdx.x;
    int idx = blockIdx.x * 512 + t;
    int v = (idx < N_NODES) ? deg[idx] : 0;
    s[t] = v;
    __syncthreads();
    for (int off = 1; off < 512; off <<= 1) {
        int a = s[t];
        if (t >= off) a += s[t - off];
        __syncthreads();
        s[t] = a;
        __syncthreads();
    }
    int excl = boff[blockIdx.x] + s[t] - v;
    if (idx < N_NODES) { row_ptr[idx] = excl; cursor[idx] = excl; }
    else if (idx == N_NODES) { row_ptr[idx] = excl; }
}

__global__ __launch_bounds__(256)
void permute_kernel(const int* __restrict__ src, const int* __restrict__ dst,
                    int* __restrict__ cursor, int* __restrict__ perm)
{
    int e = blockIdx.x * 256 + threadIdx.x;
    if (e < N_EDGES) {
        int pos = atomicAdd(&cursor[dst[e]], 1);
        perm[pos] = src[e];
    }
}

// ---------------------------------------------------------------------------
// Fused layer v2 (1024 threads, 64 output rows/block):
//   phase 1: gather agg tile into LDS — ONE node per 16-lane group (full TLP,
//            matches the standalone gather's parallelism), fp32 accum, /deg,
//            bf16 round, XOR-swizzled store.
//   phase 2: MFMA across all 16 waves: wave w -> rows 16*(w&3)..+15,
//            col-frags {(w>>2)*2, +1}; acc[2]; self rows from global (L1-hot,
//            4x shared across waves).
// mode 1: outb = bf16(relu(acc+bias)); mode 0: outf = fp32(acc+bias).
// Swizzle: short-index ^= (row&7)<<3 on BOTH write and read.
// A frag: row=lane&15, k=(lane>>4)*8+j.  C/D: col=lane&15, row=(lane>>4)*4+r.
// ---------------------------------------------------------------------------
__global__ __launch_bounds__(1024)
void fused_layer_kernel(const short* __restrict__ gsrc,   // gather source rows
                        const short* __restrict__ selfb,  // self rows (same buf)
                        const int* __restrict__ row_ptr,
                        const int* __restrict__ perm,
                        const short* __restrict__ blob,
                        const float* __restrict__ bias,
                        float* __restrict__ outf,
                        short* __restrict__ outb,
                        int mode)
{
    __shared__ short As[64 * 128];   // 16 KB agg tile (swizzled)

    const int tid = threadIdx.x;
    const int row0 = blockIdx.x * 64;

    // ---- phase 1: gather (1 node per 16-lane group) ----
    {
        const int r = tid >> 4;                 // 0..63
        const int c8 = (tid & 15) * 8;          // col offset in shorts
        int node = row0 + r;
        if (node < N_NODES) {
            int beg = row_ptr[node];
            int end = row_ptr[node + 1];
            float acc[8] = {};
            int e = beg;
            for (; e + 2 <= end; e += 2) {
                int s0 = perm[e], s1 = perm[e + 1];
                bf16x8 v0 = *reinterpret_cast<const bf16x8*>(gsrc + (size_t)s0 * D + c8);
                bf16x8 v1 = *reinterpret_cast<const bf16x8*>(gsrc + (size_t)s1 * D + c8);
                #pragma unroll
                for (int j = 0; j < 8; ++j) acc[j] += b2f(v0[j]) + b2f(v1[j]);
            }
            if (e < end) {
                int s0 = perm[e];
                bf16x8 v0 = *reinterpret_cast<const bf16x8*>(gsrc + (size_t)s0 * D + c8);
                #pragma unroll
                for (int j = 0; j < 8; ++j) acc[j] += b2f(v0[j]);
            }
            float inv = 1.0f / fmaxf((float)(end - beg), 1.0f);
            bf16x8 o;
            #pragma unroll
            for (int j = 0; j < 8; ++j) o[j] = f2bf(acc[j] * inv);
            int idx = (r * 128 + c8) ^ ((r & 7) << 3);
            *reinterpret_cast<bf16x8*>(As + idx) = o;
        }
    }
    __syncthreads();

    // ---- phase 2: MFMA (16 waves; wave w: row-group w&3, col-frags (w>>2)*2..+1) ----
    const int w = tid >> 6;             // 0..15
    const int lane = tid & 63;
    const int kch = lane >> 4;          // 0..3
    const int rg = w & 3;
    const int cb0 = (w >> 2) * 2;
    const int rloc = rg * 16 + (lane & 15);
    int row = row0 + rloc;
    int rowc = row < N_NODES ? row : N_NODES - 1;   // clamp loads; garbage unstored

    const short* selfp = selfb + (size_t)rowc * D + kch * 8;

    f32x4 acc[2] = {};

    #pragma unroll
    for (int ks = 0; ks < 8; ++ks) {
        bf16x8 a;
        if (ks < 4) {
            int idx = (rloc * 128 + ks * 32 + kch * 8) ^ ((rloc & 7) << 3);
            a = *reinterpret_cast<const bf16x8*>(As + idx);
        } else {
            a = *reinterpret_cast<const bf16x8*>(selfp + (ks - 4) * 32);
        }
        const short* bptr = blob + ((size_t)(ks * 8 + cb0) * 64 + lane) * 8;
        bf16x8 b0 = *reinterpret_cast<const bf16x8*>(bptr);
        bf16x8 b1 = *reinterpret_cast<const bf16x8*>(bptr + 64 * 8);
        acc[0] = __builtin_amdgcn_mfma_f32_16x16x32_bf16(a, b0, acc[0], 0, 0, 0);
        acc[1] = __builtin_amdgcn_mfma_f32_16x16x32_bf16(a, b1, acc[1], 0, 0, 0);
    }

    // ---- epilogue ----
    const int colg = lane & 15;
    const int rbase = row0 + rg * 16 + (lane >> 4) * 4;
    #pragma unroll
    for (int i = 0; i < 2; ++i) {
        int col = (cb0 + i) * 16 + colg;
        float bv = bias[col];
        #pragma unroll
        for (int r = 0; r < 4; ++r) {
            int rr = rbase + r;
            if (rr < N_NODES) {
                float v = acc[i][r] + bv;
                if (mode) {
                    v = fmaxf(v, 0.0f);
                    outb[(size_t)rr * D + col] = f2bf(v);
                } else {
                    outf[(size_t)rr * D + col] = v;
                }
            }
        }
    }
}

// ---------------------------------------------------------------------------
extern "C" void kernel_launch(void* const* d_in, const int* in_sizes, int n_in,
                              void* d_out, int out_size, void* d_ws, size_t ws_size,
                              hipStream_t stream)
{
    const float* x   = (const float*)d_in[0];
    const int*   ei  = (const int*)d_in[1];
    const int*   src = ei;              // edge_index[0]
    const int*   dst = ei + N_EDGES;    // edge_index[1]
    const float* Wl1 = (const float*)d_in[2];
    const float* bl1 = (const float*)d_in[3];
    const float* Wr1 = (const float*)d_in[4];
    const float* Wl2 = (const float*)d_in[5];
    const float* bl2 = (const float*)d_in[6];
    const float* Wr2 = (const float*)d_in[7];
    float* out = (float*)d_out;

    // workspace: ints | blob1,blob2 | xb (bf16) | hb (bf16)   ~54 MB
    int* deg     = (int*)d_ws;                 // N
    int* row_ptr = deg + N_NODES;              // N+1
    int* cursor  = row_ptr + N_NODES + 1;      // N
    int* bsum    = cursor + N_NODES;           // 256
    int* boff    = bsum + 256;                 // 256
    int* perm    = boff + 256;                 // E
    size_t int_end = (size_t)(3 * N_NODES + 1 + 512) + N_EDGES;   // int elements
    int_end = (int_end + 3) & ~(size_t)3;      // 16B align
    short* blob1 = (short*)((int*)d_ws + int_end);   // 4096*8 shorts
    short* blob2 = blob1 + 32768;
    short* xb    = blob2 + 32768;                    // N*D bf16
    short* hb    = xb + (size_t)N_NODES * D;         // N*D bf16 (layer-1 output)

    const int edge_blocks = (N_EDGES + 255) / 256;          // 1954
    const int scan_blocks = (N_NODES + 512) / 512;          // 196 (covers idx==N)
    const int prep_blocks = (N_NODES * D / 8) / 256;        // 6250
    const int fuse_blocks = (N_NODES + 63) / 64;            // 1563

    // ---- prep (cast + hist + pack) + CSR scans ----
    hipMemsetAsync(deg, 0, N_NODES * sizeof(int), stream);
    prep_kernel<<<prep_blocks, 256, 0, stream>>>(x, xb, dst, deg,
                                                 Wl1, Wr1, Wl2, Wr2, blob1);
    scanA_kernel<<<scan_blocks, 512, 0, stream>>>(deg, bsum);
    scanB_kernel<<<1, 256, 0, stream>>>(bsum, boff);
    scanC_kernel<<<scan_blocks, 512, 0, stream>>>(deg, boff, row_ptr, cursor);
    permute_kernel<<<edge_blocks, 256, 0, stream>>>(src, dst, cursor, perm);

    // ---- layer 1: hb = bf16(relu(agg(xb)@Wl1 + b + xb@Wr1)) ----
    fused_layer_kernel<<<fuse_blocks, 1024, 0, stream>>>(xb, xb, row_ptr, perm,
                                                         blob1, bl1, nullptr, hb, 1);

    // ---- layer 2: out = agg(hb)@Wl2 + b + hb@Wr2 (fp32) ----
    fused_layer_kernel<<<fuse_blocks, 1024, 0, stream>>>(hb, hb, row_ptr, perm,
                                                         blob2, bl2, out, nullptr, 0);
}